// Round 1
// baseline (232.771 us; speedup 1.0000x reference)
//
#include <hip/hip_runtime.h>

// AutoEncoderLoss: two-level segment-mean MSE.
//   seg = batch_index*C + clabel ; sums/counts over 4096 segments;
//   per-(b,c) mean -> mean over present clusters per batch -> mean over present batches.
// B=32, C=128 fixed by the reference setup.

#define BATCHES 32
#define CLUSTERS 128
#define NSEG (BATCHES * CLUSTERS)
#define BLOCK 256
#define ELEMS_PER_BLOCK 4096  // 256 threads x 4 iters x float4

__global__ __launch_bounds__(BLOCK) void seg_accum_kernel(
    const float* __restrict__ reco,
    const float* __restrict__ target,
    const int* __restrict__ clabel,
    const int* __restrict__ batch_index,
    float* __restrict__ gsum,
    float* __restrict__ gcnt,
    int n)
{
    __shared__ float lsum[NSEG];
    __shared__ float lcnt[NSEG];
    const int tid = threadIdx.x;

    #pragma unroll
    for (int s = tid; s < NSEG; s += BLOCK) { lsum[s] = 0.0f; lcnt[s] = 0.0f; }
    __syncthreads();

    // Contiguous chunk per block: batch_index is sorted, so a block sees
    // <=2 distinct batches -> few hot LDS segments, sparse global flush.
    const long long base = (long long)blockIdx.x * ELEMS_PER_BLOCK;

    #pragma unroll
    for (int k = 0; k < 4; ++k) {
        const long long idx = base + (long long)(k * BLOCK + tid) * 4;
        if (idx + 3 < (long long)n) {
            const float4 r = *(const float4*)(reco + idx);
            const float4 t = *(const float4*)(target + idx);
            const int4   c = *(const int4*)(clabel + idx);
            const int4   b = *(const int4*)(batch_index + idx);
            float d;
            d = r.x - t.x; atomicAdd(&lsum[b.x * CLUSTERS + c.x], d * d);
                           atomicAdd(&lcnt[b.x * CLUSTERS + c.x], 1.0f);
            d = r.y - t.y; atomicAdd(&lsum[b.y * CLUSTERS + c.y], d * d);
                           atomicAdd(&lcnt[b.y * CLUSTERS + c.y], 1.0f);
            d = r.z - t.z; atomicAdd(&lsum[b.z * CLUSTERS + c.z], d * d);
                           atomicAdd(&lcnt[b.z * CLUSTERS + c.z], 1.0f);
            d = r.w - t.w; atomicAdd(&lsum[b.w * CLUSTERS + c.w], d * d);
                           atomicAdd(&lcnt[b.w * CLUSTERS + c.w], 1.0f);
        } else if (idx < (long long)n) {
            for (long long j = idx; j < (long long)n; ++j) {
                const float d = reco[j] - target[j];
                const int s = batch_index[j] * CLUSTERS + clabel[j];
                atomicAdd(&lsum[s], d * d);
                atomicAdd(&lcnt[s], 1.0f);
            }
        }
    }
    __syncthreads();

    for (int s = tid; s < NSEG; s += BLOCK) {
        const float cv = lcnt[s];
        if (cv != 0.0f) {
            atomicAdd(&gsum[s], lsum[s]);
            atomicAdd(&gcnt[s], cv);
        }
    }
}

__global__ __launch_bounds__(64) void finalize_kernel(
    const float* __restrict__ gsum,
    const float* __restrict__ gcnt,
    float* __restrict__ out)
{
    __shared__ float bl[BATCHES];
    __shared__ float bp[BATCHES];
    const int tid = threadIdx.x;

    if (tid < BATCHES) {
        float sm = 0.0f, np = 0.0f;
        for (int c = 0; c < CLUSTERS; ++c) {
            const float cnt = gcnt[tid * CLUSTERS + c];
            if (cnt > 0.0f) {
                sm += gsum[tid * CLUSTERS + c] / cnt;
                np += 1.0f;
            }
        }
        bl[tid] = (np > 0.0f) ? (sm / np) : 0.0f;
        bp[tid] = (np > 0.0f) ? 1.0f : 0.0f;
    }
    __syncthreads();

    if (tid == 0) {
        float s = 0.0f, nb = 0.0f;
        for (int b = 0; b < BATCHES; ++b) { s += bl[b]; nb += bp[b]; }
        out[0] = (nb > 0.0f) ? (s / nb) : 0.0f;
    }
}

extern "C" void kernel_launch(void* const* d_in, const int* in_sizes, int n_in,
                              void* d_out, int out_size, void* d_ws, size_t ws_size,
                              hipStream_t stream) {
    const float* reco        = (const float*)d_in[0];
    const float* target      = (const float*)d_in[1];
    const int*   clabel      = (const int*)d_in[2];
    const int*   batch_index = (const int*)d_in[3];
    const int n = in_sizes[0];

    float* gsum = (float*)d_ws;
    float* gcnt = gsum + NSEG;

    // d_ws is re-poisoned to 0xAA before every launch -> must zero each call.
    hipMemsetAsync(d_ws, 0, 2 * NSEG * sizeof(float), stream);

    const int nblocks = (n + ELEMS_PER_BLOCK - 1) / ELEMS_PER_BLOCK;
    seg_accum_kernel<<<nblocks, BLOCK, 0, stream>>>(
        reco, target, clabel, batch_index, gsum, gcnt, n);
    finalize_kernel<<<1, 64, 0, stream>>>(gsum, gcnt, (float*)d_out);
}

// Round 2
// 160.616 us; speedup vs baseline: 1.4492x; 1.4492x over previous
//
#include <hip/hip_runtime.h>

// AutoEncoderLoss: two-level segment-mean MSE over seg = b*128 + c.
// Strategy: per-wave-replicated LDS histogram of PACKED u64 accumulators
//   enc = (1 << 44) | round(d^2 * 2^20)   (count in high bits, fixed-point sum low)
// -> ONE native integer ds_add_u64 per element (no FP-atomic CAS loops).
// batch_index is sorted: per-block chunk is single-batch except ~31/2048
// boundary blocks -> fast path skips the per-element batch load entirely.

#define BATCHES 32
#define CLUSTERS 128
#define NSEG (BATCHES * CLUSTERS)
#define BLOCK 256
#define WAVES 4
#define EPB 4096                 // elements per block = 256 threads x 4 iters x 4
#define SHIFT 44
#define SCALE 1048576.0f         // 2^20
#define INV_SCALE (1.0f / 1048576.0f)
#define SUM_MASK ((1ULL << SHIFT) - 1)

typedef unsigned long long u64;

__device__ __forceinline__ u64 enc_elem(float d) {
    return (1ULL << SHIFT) + (u64)__float2uint_rn(d * d * SCALE);
}

__global__ __launch_bounds__(BLOCK) void seg_accum_kernel(
    const float* __restrict__ reco,
    const float* __restrict__ target,
    const int* __restrict__ clabel,
    const int* __restrict__ batch_index,
    u64* __restrict__ gseg,
    int n)
{
    // per-wave replica, 2 batches (b0, b0+1) x 128 clusters each
    __shared__ u64 hist[WAVES][2 * CLUSTERS];
    const int tid  = threadIdx.x;
    const int wave = tid >> 6;

    for (int s = tid; s < WAVES * 2 * CLUSTERS; s += BLOCK)
        ((u64*)hist)[s] = 0ULL;
    __syncthreads();

    const long long base = (long long)blockIdx.x * EPB;
    if (base >= n) return;  // uniform per block, safe vs barriers
    const long long lim = (base + EPB <= (long long)n) ? base + EPB : (long long)n;

    const int b0 = batch_index[base];
    const int bL = batch_index[lim - 1];
    u64* h = hist[wave];

    if (b0 == bL && base + EPB <= (long long)n) {
        // single-batch full chunk: no per-element batch load
        #pragma unroll
        for (int k = 0; k < EPB / (BLOCK * 4); ++k) {
            const long long idx = base + (long long)(k * BLOCK + tid) * 4;
            const float4 r = *(const float4*)(reco + idx);
            const float4 t = *(const float4*)(target + idx);
            const int4   c = *(const int4*)(clabel + idx);
            atomicAdd(&h[c.x], enc_elem(r.x - t.x));
            atomicAdd(&h[c.y], enc_elem(r.y - t.y));
            atomicAdd(&h[c.z], enc_elem(r.z - t.z));
            atomicAdd(&h[c.w], enc_elem(r.w - t.w));
        }
    } else {
        // boundary / tail path (rare): per-element batch
        for (long long idx = base + tid; idx < lim; idx += BLOCK) {
            const float d = reco[idx] - target[idx];
            const int b = batch_index[idx];
            const int c = clabel[idx];
            const u64 enc = enc_elem(d);
            const int rel = b - b0;
            if (rel < 2) atomicAdd(&h[rel * CLUSTERS + c], enc);
            else         atomicAdd(&gseg[(long long)b * CLUSTERS + c], enc);  // ~never
        }
    }
    __syncthreads();

    // combine wave replicas, sparse flush (zero entries skipped -> no OOB
    // for the unused upper half when b0 is the last batch)
    for (int s = tid; s < 2 * CLUSTERS; s += BLOCK) {
        const u64 v = hist[0][s] + hist[1][s] + hist[2][s] + hist[3][s];
        if (v) atomicAdd(&gseg[(long long)b0 * CLUSTERS + s], v);
    }
}

__global__ __launch_bounds__(256) void finalize_kernel(
    const u64* __restrict__ gseg,
    float* __restrict__ out)
{
    __shared__ float bl[BATCHES];
    __shared__ float bp[BATCHES];
    const int tid  = threadIdx.x;
    const int b    = tid >> 3;   // 32 batches x 8 threads
    const int part = tid & 7;

    float sm = 0.0f, np = 0.0f;
    #pragma unroll
    for (int j = 0; j < 16; ++j) {
        const u64 v = gseg[b * CLUSTERS + part * 16 + j];
        if (v) {  // nonzero iff count > 0
            const float cnt = (float)(unsigned)(v >> SHIFT);
            const float sum = (float)(v & SUM_MASK) * INV_SCALE;
            sm += sum / cnt;
            np += 1.0f;
        }
    }
    // reduce across the 8 threads per batch (contiguous lanes within a wave)
    #pragma unroll
    for (int off = 4; off; off >>= 1) {
        sm += __shfl_down(sm, off, 8);
        np += __shfl_down(np, off, 8);
    }
    if (part == 0) {
        bl[b] = (np > 0.0f) ? (sm / np) : 0.0f;
        bp[b] = (np > 0.0f) ? 1.0f : 0.0f;
    }
    __syncthreads();

    if (tid == 0) {
        float s = 0.0f, nb = 0.0f;
        #pragma unroll
        for (int i = 0; i < BATCHES; ++i) { s += bl[i]; nb += bp[i]; }
        out[0] = (nb > 0.0f) ? (s / nb) : 0.0f;
    }
}

extern "C" void kernel_launch(void* const* d_in, const int* in_sizes, int n_in,
                              void* d_out, int out_size, void* d_ws, size_t ws_size,
                              hipStream_t stream) {
    const float* reco        = (const float*)d_in[0];
    const float* target      = (const float*)d_in[1];
    const int*   clabel      = (const int*)d_in[2];
    const int*   batch_index = (const int*)d_in[3];
    const int n = in_sizes[0];

    u64* gseg = (u64*)d_ws;
    hipMemsetAsync(d_ws, 0, NSEG * sizeof(u64), stream);  // ws re-poisoned every call

    const int nblocks = (n + EPB - 1) / EPB;
    seg_accum_kernel<<<nblocks, BLOCK, 0, stream>>>(
        reco, target, clabel, batch_index, gseg, n);
    finalize_kernel<<<1, 256, 0, stream>>>(gseg, (float*)d_out);
}